// Round 22
// baseline (622.774 us; speedup 1.0000x reference)
//
#include <hip/hip_runtime.h>
#include <math.h>

// Problem constants (reference: POS_LEN=32, NUM_F=16, HIDDEN=256, T=32)
#define NUM_F   16
#define FIN     (8 * NUM_F)      // 128 fourier features
#define HIDDEN  256
#define TOUT    32
#define NOFF    63               // distinct offset values: -31..31
#define NSUM    125              // distinct dr+dc / dr-dc values: -62..62
#define NPAIRS_TBL (NOFF * NOFF) // 3969
#define PROWS   (NOFF + NOFF + NSUM + NSUM)      // 376 rows in P
#define NCHUNKS ((NPAIRS_TBL + 3) / 4)           // 993 KT chunks of 4 pairs
#define NROWS   1024                             // output rows (S)

// ws offsets
#define TBL_B   ((size_t)NPAIRS_TBL * TOUT * 4)  // 508032
#define P_B     ((size_t)PROWS * HIDDEN * 4)     // 385024
#define CNT_OFF (TBL_B + P_B)                    // 893056; qB,qC,cnt[63]

// ---------------------------------------------------------------------------
// KP: layer-1 separable partials P[rho][h] (proven ~1.5 us). Block 0 also
// zeroes the counter block (stream order puts this before the mega kernel).
__global__ __launch_bounds__(256) void gab_ptab_kernel(
    const float* __restrict__ freqs, const float* __restrict__ W1,
    float* __restrict__ P, int* __restrict__ counters)
{
    __shared__ float fv[32];
    const int t = threadIdx.x;
    if (blockIdx.x == 0 && t < 128) counters[t] = 0;

    const int rho = blockIdx.x;
    int grp, val;
    if (rho < NOFF)                 { grp = 0; val = rho - 31; }
    else if (rho < 2 * NOFF)        { grp = 1; val = rho - NOFF - 31; }
    else if (rho < 2 * NOFF + NSUM) { grp = 2; val = rho - 2 * NOFF - 62; }
    else                            { grp = 3; val = rho - 2 * NOFF - NSUM - 62; }
    if (t < 32) {
        const float arg = (float)val * freqs[t & 15];
        fv[t] = (t < 16) ? sinf(arg) : cosf(arg);   // [sin16, cos16]
    }
    __syncthreads();
    const float4* __restrict__ w4 = (const float4*)(W1 + t * FIN + grp * 32);
    const float4* f4 = (const float4*)fv;           // same-addr broadcast
    float a0 = 0.f, a1 = 0.f, a2 = 0.f, a3 = 0.f;
    #pragma unroll
    for (int k = 0; k < 8; k += 2) {
        const float4 wa = w4[k], wb = w4[k + 1];
        const float4 fa = f4[k], fb = f4[k + 1];
        a0 = fmaf(wa.x, fa.x, a0); a1 = fmaf(wa.y, fa.y, a1);
        a2 = fmaf(wa.z, fa.z, a2); a3 = fmaf(wa.w, fa.w, a3);
        a0 = fmaf(wb.x, fb.x, a0); a1 = fmaf(wb.y, fb.y, a1);
        a2 = fmaf(wb.z, fb.z, a2); a3 = fmaf(wb.w, fb.w, a3);
    }
    P[rho * HIDDEN + t] = (a0 + a1) + (a2 + a3);
}

// ---------------------------------------------------------------------------
// Mega: work-stealing {KT chunks} then {gather rows with per-band waits}.
// Deadlock-free: every block drains the KT queue BEFORE any spin, so all
// claimed KT work completes and cnt[ia] reaches 63.
__global__ __launch_bounds__(256) void gab_mega_kernel(
    const float* __restrict__ P, const float* __restrict__ b1,
    const float* __restrict__ W2, const float* __restrict__ b2,
    float* __restrict__ table, float4* __restrict__ out,
    int* __restrict__ counters)
{
    __shared__ int sC[1];
    int* qB  = counters + 0;
    int* qC  = counters + 1;
    int* cnt = counters + 2;                  // cnt[0..62]

    const int t = threadIdx.x;
    const int w = t >> 6;
    const int l = t & 63;

    // ================= Phase B: KT chunks (4 pairs, 1 per wave) ===========
    for (;;) {
        if (t == 0) sC[0] = atomicAdd(qB, 1);
        __syncthreads();
        const int c = sC[0];
        __syncthreads();
        if (c >= NCHUNKS) break;

        const int pair = c * 4 + w;
        const bool valid = (pair < NPAIRS_TBL);
        const int cp = valid ? pair : (NPAIRS_TBL - 1);
        const int ia = cp / NOFF;
        const int ib = cp % NOFF;
        const int ip = ia + ib;
        const int im = ia - ib + 62;
        const float4* __restrict__ P4 = (const float4*)P;
        const float4 pa = P4[(0 * NOFF          + ia) * 64 + l];
        const float4 pb = P4[(1 * NOFF          + ib) * 64 + l];
        const float4 pp = P4[(2 * NOFF          + ip) * 64 + l];
        const float4 pm = P4[((2 * NOFF + NSUM) + im) * 64 + l];
        const float4 bb = ((const float4*)b1)[l];
        float h0 = pa.x + pb.x + pp.x + pm.x + bb.x;
        float h1 = pa.y + pb.y + pp.y + pm.y + bb.y;
        float h2 = pa.z + pb.z + pp.z + pm.z + bb.z;
        float h3 = pa.w + pb.w + pp.w + pm.w + bb.w;
        h0 = h0 / (1.0f + expf(-h0));
        h1 = h1 / (1.0f + expf(-h1));
        h2 = h2 / (1.0f + expf(-h2));
        h3 = h3 / (1.0f + expf(-h3));

        float acc[32];
        const float4* __restrict__ W24 = (const float4*)W2;
        #pragma unroll
        for (int o = 0; o < 32; ++o) {
            const float4 ww = W24[o * 64 + l];
            acc[o] = fmaf(ww.x, h0, fmaf(ww.y, h1, fmaf(ww.z, h2, ww.w * h3)));
        }
        #pragma unroll
        for (int i = 0; i < 16; ++i) {
            const float keep = (l & 1) ? acc[i + 16] : acc[i];
            const float send = (l & 1) ? acc[i] : acc[i + 16];
            acc[i] = keep + __shfl_xor(send, 1);
        }
        #pragma unroll
        for (int i = 0; i < 8; ++i) {
            const float keep = (l & 2) ? acc[i + 8] : acc[i];
            const float send = (l & 2) ? acc[i] : acc[i + 8];
            acc[i] = keep + __shfl_xor(send, 2);
        }
        #pragma unroll
        for (int i = 0; i < 4; ++i) {
            const float keep = (l & 4) ? acc[i + 4] : acc[i];
            const float send = (l & 4) ? acc[i] : acc[i + 4];
            acc[i] = keep + __shfl_xor(send, 4);
        }
        #pragma unroll
        for (int i = 0; i < 2; ++i) {
            const float keep = (l & 8) ? acc[i + 2] : acc[i];
            const float send = (l & 8) ? acc[i] : acc[i + 2];
            acc[i] = keep + __shfl_xor(send, 8);
        }
        {
            const float keep = (l & 16) ? acc[1] : acc[0];
            const float send = (l & 16) ? acc[0] : acc[1];
            acc[0] = keep + __shfl_xor(send, 16);
        }
        const float tot = acc[0] + __shfl_xor(acc[0], 32);
        if (valid && l < 32) {
            const int o = ((l & 1) << 4) | ((l & 2) << 2) | (l & 4)
                        | ((l & 8) >> 2) | ((l & 16) >> 4);   // bitrev5(l)
            table[pair * TOUT + o] = (tot + b2[o]) * 0.17677669529663687f;
        }
        __threadfence();                       // release pair's row
        if (valid && l == 0) atomicAdd(&cnt[ia], 1);
    }

    // ================= Phase C: gather rows (sequential writes) ===========
    const float4* __restrict__ tbl4 = (const float4*)table;
    for (;;) {
        if (t == 0) sC[0] = atomicAdd(qC, 1);
        __syncthreads();
        const int row = sC[0];
        __syncthreads();
        if (row >= NROWS) break;

        const int bi = row >> 5;
        if (t == 0) {                          // wait for bands [bi, bi+31]
            for (int a = bi; a < bi + 32; ++a) {
                while (__hip_atomic_load(&cnt[a], __ATOMIC_ACQUIRE,
                                         __HIP_MEMORY_SCOPE_AGENT) < NOFF)
                    __builtin_amdgcn_s_sleep(8);
            }
        }
        __syncthreads();
        __threadfence();                       // acquire for all threads

        const int i    = row;
        const int irh  = i >> 5, irl = i & 31;
        const int base = row * 8192;           // f4 index of row start
        #pragma unroll 4
        for (int k = 0; k < 32; ++k) {
            const int idx = base + k * 256 + t;
            const int p  = idx >> 3;
            const int lq = idx & 7;
            const int j  = p & 1023;
            const int ir = irh - (j >> 5) + 31;
            const int ic = irl - (j & 31) + 31;
            out[idx] = tbl4[(ir * NOFF + ic) * 8 + lq];
        }
    }
}

// ---------------------------------------------------------------------------
// Fallback: R19 (34.7 us proven) if ws too small for counters.
__global__ __launch_bounds__(256) void gab_scatter_kernel(
    const float* __restrict__ P, const float* __restrict__ b1,
    const float* __restrict__ W2, const float* __restrict__ b2,
    float4* __restrict__ out)
{
    __shared__ float rowLDS[32];
    const int t = threadIdx.x;
    const int l = t & 63;
    const int pair = blockIdx.x;
    const int ia = pair / NOFF;
    const int ib = pair % NOFF;
    const int dr = ia - 31, dc = ib - 31;

    if (t < 64) {
        const int ip = ia + ib;
        const int im = ia - ib + 62;
        const float4* __restrict__ P4 = (const float4*)P;
        const float4 pa = P4[(0 * NOFF          + ia) * 64 + l];
        const float4 pb = P4[(1 * NOFF          + ib) * 64 + l];
        const float4 pp = P4[(2 * NOFF          + ip) * 64 + l];
        const float4 pm = P4[((2 * NOFF + NSUM) + im) * 64 + l];
        const float4 bb = ((const float4*)b1)[l];
        float h0 = pa.x + pb.x + pp.x + pm.x + bb.x;
        float h1 = pa.y + pb.y + pp.y + pm.y + bb.y;
        float h2 = pa.z + pb.z + pp.z + pm.z + bb.z;
        float h3 = pa.w + pb.w + pp.w + pm.w + bb.w;
        h0 = h0 / (1.0f + expf(-h0));
        h1 = h1 / (1.0f + expf(-h1));
        h2 = h2 / (1.0f + expf(-h2));
        h3 = h3 / (1.0f + expf(-h3));
        float acc[32];
        const float4* __restrict__ W24 = (const float4*)W2;
        #pragma unroll
        for (int o = 0; o < 32; ++o) {
            const float4 ww = W24[o * 64 + l];
            acc[o] = fmaf(ww.x, h0, fmaf(ww.y, h1, fmaf(ww.z, h2, ww.w * h3)));
        }
        #pragma unroll
        for (int i = 0; i < 16; ++i) {
            const float keep = (l & 1) ? acc[i + 16] : acc[i];
            const float send = (l & 1) ? acc[i] : acc[i + 16];
            acc[i] = keep + __shfl_xor(send, 1);
        }
        #pragma unroll
        for (int i = 0; i < 8; ++i) {
            const float keep = (l & 2) ? acc[i + 8] : acc[i];
            const float send = (l & 2) ? acc[i] : acc[i + 8];
            acc[i] = keep + __shfl_xor(send, 2);
        }
        #pragma unroll
        for (int i = 0; i < 4; ++i) {
            const float keep = (l & 4) ? acc[i + 4] : acc[i];
            const float send = (l & 4) ? acc[i] : acc[i + 4];
            acc[i] = keep + __shfl_xor(send, 4);
        }
        #pragma unroll
        for (int i = 0; i < 2; ++i) {
            const float keep = (l & 8) ? acc[i + 2] : acc[i];
            const float send = (l & 8) ? acc[i] : acc[i + 2];
            acc[i] = keep + __shfl_xor(send, 8);
        }
        {
            const float keep = (l & 16) ? acc[1] : acc[0];
            const float send = (l & 16) ? acc[0] : acc[1];
            acc[0] = keep + __shfl_xor(send, 16);
        }
        const float tot = acc[0] + __shfl_xor(acc[0], 32);
        if (l < 32) {
            const int o = ((l & 1) << 4) | ((l & 2) << 2) | (l & 4)
                        | ((l & 8) >> 2) | ((l & 16) >> 4);
            rowLDS[o] = (tot + b2[o]) * 0.17677669529663687f;
        }
    }
    __syncthreads();
    const float4 quad = ((const float4*)rowLDS)[t & 7];
    const int brmin = (dr > 0) ? dr : 0;
    const int irmin = (dc > 0) ? dc : 0;
    const int wc = 32 - ((dc < 0) ? -dc : dc);
    const int hb = 32 - ((dr < 0) ? -dr : dr);
    const int count = hb * wc;
    const unsigned M = ((1u << 20) + (unsigned)wc - 1) / (unsigned)wc;
    const int mybase = t >> 3;
    const int o4 = t & 7;
    for (int m = mybase; m < count; m += 32) {
        const int q2 = (int)(((unsigned)m * M) >> 20);
        const int r2 = m - q2 * wc;
        const int i = ((brmin + q2) << 5) + (irmin + r2);
        const int j = ((brmin + q2 - dr) << 5) + (irmin + r2 - dc);
        out[(((i << 10) + j) << 3) + o4] = quad;
    }
}

// ---------------------------------------------------------------------------
extern "C" void kernel_launch(void* const* d_in, const int* in_sizes, int n_in,
                              void* d_out, int out_size, void* d_ws, size_t ws_size,
                              hipStream_t stream) {
    // inputs: 0 seq_len 1 freqs(16) 2 W1(256*128) 3 b1(256) 4 W2(32*256)
    //         5 b2(32) 6 dr(S*S) 7 dc(S*S)
    const float* freqs = (const float*)d_in[1];
    const float* W1    = (const float*)d_in[2];
    const float* b1    = (const float*)d_in[3];
    const float* W2    = (const float*)d_in[4];
    const float* b2    = (const float*)d_in[5];
    float4* out = (float4*)d_out;

    float* table   = (float*)d_ws;
    float* P       = (float*)((char*)d_ws + TBL_B);
    int*   counters = (int*)((char*)d_ws + CNT_OFF);

    if (ws_size >= CNT_OFF + 512) {
        gab_ptab_kernel<<<PROWS, 256, 0, stream>>>(freqs, W1, P, counters);
        gab_mega_kernel<<<2048, 256, 0, stream>>>(P, b1, W2, b2, table, out, counters);
    } else {
        gab_ptab_kernel   <<<PROWS, 256, 0, stream>>>(freqs, W1, P, counters);
        gab_scatter_kernel<<<NPAIRS_TBL, 256, 0, stream>>>(P, b1, W2, b2, out);
    }
}

// Round 23
// 34.694 us; speedup vs baseline: 17.9506x; 17.9506x over previous
//
#include <hip/hip_runtime.h>
#include <math.h>

// Problem constants (reference: POS_LEN=32, NUM_F=16, HIDDEN=256, T=32)
#define NUM_F   16
#define FIN     (8 * NUM_F)      // 128 fourier features
#define HIDDEN  256
#define TOUT    32
#define NOFF    63               // distinct offset values: -31..31
#define NSUM    125              // distinct dr+dc / dr-dc values: -62..62
#define NPAIRS_TBL (NOFF * NOFF) // 3969
#define PROWS   (NOFF + NOFF + NSUM + NSUM)      // 376 rows in P

// ---------------------------------------------------------------------------
// KP: layer-1 separable partials P[rho][h] (proven ~1.5 us, plain stores).
//   rho 0..62 Pa(dr) | 63..125 Pb(dc) | 126..250 Pp(dr+dc) | 251..375 Pm(dr-dc)
__global__ __launch_bounds__(256) void gab_ptab_kernel(
    const float* __restrict__ freqs, const float* __restrict__ W1,
    float* __restrict__ P)
{
    __shared__ float fv[32];
    const int rho = blockIdx.x;
    int grp, val;
    if (rho < NOFF)                 { grp = 0; val = rho - 31; }
    else if (rho < 2 * NOFF)        { grp = 1; val = rho - NOFF - 31; }
    else if (rho < 2 * NOFF + NSUM) { grp = 2; val = rho - 2 * NOFF - 62; }
    else                            { grp = 3; val = rho - 2 * NOFF - NSUM - 62; }
    const int t = threadIdx.x;
    if (t < 32) {
        const float arg = (float)val * freqs[t & 15];
        fv[t] = (t < 16) ? sinf(arg) : cosf(arg);   // [sin16, cos16]
    }
    __syncthreads();
    const float4* __restrict__ w4 = (const float4*)(W1 + t * FIN + grp * 32);
    const float4* f4 = (const float4*)fv;           // same-addr broadcast
    float a0 = 0.f, a1 = 0.f, a2 = 0.f, a3 = 0.f;
    #pragma unroll
    for (int k = 0; k < 8; k += 2) {
        const float4 wa = w4[k], wb = w4[k + 1];
        const float4 fa = f4[k], fb = f4[k + 1];
        a0 = fmaf(wa.x, fa.x, a0); a1 = fmaf(wa.y, fa.y, a1);
        a2 = fmaf(wa.z, fa.z, a2); a3 = fmaf(wa.w, fa.w, a3);
        a0 = fmaf(wb.x, fb.x, a0); a1 = fmaf(wb.y, fb.y, a1);
        a2 = fmaf(wb.z, fb.z, a2); a3 = fmaf(wb.w, fb.w, a3);
    }
    P[rho * HIDDEN + t] = (a0 + a1) + (a2 + a3);
}

// ---------------------------------------------------------------------------
// Scatter v2 (R19, best measured 34.7 us): one BLOCK per pair. Wave 0
// computes the pair's 32-float row (proven R7 structure), writes it to LDS;
// all 4 waves then stream the pair's (i,j) rectangle with float4 stores —
// 8 consecutive 128-B lines per wave-instruction. Compute + cold P/W2
// misses hide under co-resident blocks' store streams.
__global__ __launch_bounds__(256) void gab_scatter_kernel(
    const float* __restrict__ P, const float* __restrict__ b1,
    const float* __restrict__ W2, const float* __restrict__ b2,
    float4* __restrict__ out)
{
    __shared__ float rowLDS[32];

    const int t    = threadIdx.x;
    const int l    = t & 63;
    const int pair = blockIdx.x;

    const int ia = pair / NOFF;               // dr + 31
    const int ib = pair % NOFF;               // dc + 31
    const int dr = ia - 31, dc = ib - 31;

    if (t < 64) {                             // wave 0: row compute
        const int ip = ia + ib;
        const int im = ia - ib + 62;
        const float4* __restrict__ P4 = (const float4*)P;
        const float4 pa = P4[(0 * NOFF          + ia) * 64 + l];
        const float4 pb = P4[(1 * NOFF          + ib) * 64 + l];
        const float4 pp = P4[(2 * NOFF          + ip) * 64 + l];
        const float4 pm = P4[((2 * NOFF + NSUM) + im) * 64 + l];
        const float4 bb = ((const float4*)b1)[l];
        float h0 = pa.x + pb.x + pp.x + pm.x + bb.x;
        float h1 = pa.y + pb.y + pp.y + pm.y + bb.y;
        float h2 = pa.z + pb.z + pp.z + pm.z + bb.z;
        float h3 = pa.w + pb.w + pp.w + pm.w + bb.w;
        h0 = h0 / (1.0f + expf(-h0));
        h1 = h1 / (1.0f + expf(-h1));
        h2 = h2 / (1.0f + expf(-h2));
        h3 = h3 / (1.0f + expf(-h3));

        float acc[32];
        const float4* __restrict__ W24 = (const float4*)W2;
        #pragma unroll
        for (int o = 0; o < 32; ++o) {
            const float4 w = W24[o * 64 + l];           // coalesced, L2-hot
            acc[o] = fmaf(w.x, h0, fmaf(w.y, h1, fmaf(w.z, h2, w.w * h3)));
        }
        #pragma unroll
        for (int i = 0; i < 16; ++i) {
            const float keep = (l & 1) ? acc[i + 16] : acc[i];
            const float send = (l & 1) ? acc[i] : acc[i + 16];
            acc[i] = keep + __shfl_xor(send, 1);
        }
        #pragma unroll
        for (int i = 0; i < 8; ++i) {
            const float keep = (l & 2) ? acc[i + 8] : acc[i];
            const float send = (l & 2) ? acc[i] : acc[i + 8];
            acc[i] = keep + __shfl_xor(send, 2);
        }
        #pragma unroll
        for (int i = 0; i < 4; ++i) {
            const float keep = (l & 4) ? acc[i + 4] : acc[i];
            const float send = (l & 4) ? acc[i] : acc[i + 4];
            acc[i] = keep + __shfl_xor(send, 4);
        }
        #pragma unroll
        for (int i = 0; i < 2; ++i) {
            const float keep = (l & 8) ? acc[i + 2] : acc[i];
            const float send = (l & 8) ? acc[i] : acc[i + 2];
            acc[i] = keep + __shfl_xor(send, 8);
        }
        {
            const float keep = (l & 16) ? acc[1] : acc[0];
            const float send = (l & 16) ? acc[0] : acc[1];
            acc[0] = keep + __shfl_xor(send, 16);
        }
        const float tot = acc[0] + __shfl_xor(acc[0], 32);
        if (l < 32) {
            const int o = ((l & 1) << 4) | ((l & 2) << 2) | (l & 4)
                        | ((l & 8) >> 2) | ((l & 16) >> 4);   // bitrev5(l)
            rowLDS[o] = (tot + b2[o]) * 0.17677669529663687f; // /sqrt(32)
        }
    }
    __syncthreads();                           // row ready for all waves

    const float4 quad = ((const float4*)rowLDS)[t & 7];  // broadcast read

    // ---- stream the rectangle: thread t -> (line m = it*32 + t>>3, quad) --
    const int brmin = (dr > 0) ? dr : 0;
    const int irmin = (dc > 0) ? dc : 0;
    const int wc = 32 - ((dc < 0) ? -dc : dc);
    const int hb = 32 - ((dr < 0) ? -dr : dr);
    const int count = hb * wc;                 // 128-B lines for this pair
    const unsigned M = ((1u << 20) + (unsigned)wc - 1) / (unsigned)wc;
    const int mybase = t >> 3;                 // line slot within iteration
    const int o4 = t & 7;

    for (int m = mybase; m < count; m += 32) {
        const int q = (int)(((unsigned)m * M) >> 20);   // m / wc (exact)
        const int r = m - q * wc;                       // m % wc
        const int i = ((brmin + q) << 5) + (irmin + r);
        const int j = ((brmin + q - dr) << 5) + (irmin + r - dc);
        out[(((i << 10) + j) << 3) + o4] = quad;
    }
}

// ---------------------------------------------------------------------------
extern "C" void kernel_launch(void* const* d_in, const int* in_sizes, int n_in,
                              void* d_out, int out_size, void* d_ws, size_t ws_size,
                              hipStream_t stream) {
    // inputs: 0 seq_len 1 freqs(16) 2 W1(256*128) 3 b1(256) 4 W2(32*256)
    //         5 b2(32) 6 dr(S*S) 7 dc(S*S)
    const float* freqs = (const float*)d_in[1];
    const float* W1    = (const float*)d_in[2];
    const float* b1    = (const float*)d_in[3];
    const float* W2    = (const float*)d_in[4];
    const float* b2    = (const float*)d_in[5];
    float4* out = (float4*)d_out;

    float* P = (float*)d_ws;                   // 376*256*4 = 385 KB scratch

    gab_ptab_kernel   <<<PROWS, 256, 0, stream>>>(freqs, W1, P);
    gab_scatter_kernel<<<NPAIRS_TBL, 256, 0, stream>>>(P, b1, W2, b2, out);
}